// Round 6
// baseline (176.931 us; speedup 1.0000x reference)
//
#include <hip/hip_runtime.h>

// q,k,v: [B=8, d=768, N=6144] fp32; head_dim=32, kernel_size=3
// h = 24 heads, g = 2048 windows; window elem j of window gg at n = j*2048 + gg
// out flat: [b][gg][hh][kq][dd] contiguous [8, 2048, 24, 3, 32]
//
// Round 6: 4 threads per window (dd-octets), lane = slice*16 + wl.
//  - VGPR target <=64 (o-buffer 24 regs, v preloaded 24 regs but s/p overlap)
//    forced via __launch_bounds__(256, 8) -> 8 waves/SIMD (32/CU), double the
//    round-5 residency that was capped by the 68-VGPR occupancy cliff.
//  - v loaded into registers BEFORE shuffle-combine+softmax: its latency
//    hides under the VALU phase; PV runs register-only. ~2 serial memory
//    waits per wave instead of ~6.
//  - scores combined across the 4 slices with shfl_xor(16) + shfl_xor(32).
//  - stores: per window-row (128B) two adjacent slice-pair instructions
//    complete each 64B line -> merges in L2, no write amplification.
constexpr int CB = 8;
constexpr int CD = 768;
constexpr int CN = 6144;
constexpr int HD = 32;
constexpr int KS = 3;
constexpr int CH = CD / HD;   // 24
constexpr int CG = CN / KS;   // 2048

__global__ __launch_bounds__(256, 8) void dilate_attn_kernel(
    const float* __restrict__ q, const float* __restrict__ k,
    const float* __restrict__ v, float* __restrict__ out) {
  const int tid   = blockIdx.x * 256 + threadIdx.x;
  const int lane  = threadIdx.x & 63;
  const int wav   = tid >> 6;            // 0..24575
  const int slice = lane >> 4;           // dd-octet: dd = slice*8 .. slice*8+7
  const int wl    = lane & 15;           // window within wave
  const int gg    = (wav & 127) * 16 + wl;  // 128 waves cover one (b,hh)
  const int bh    = wav >> 7;            // b*24 + hh
  const int hh    = bh % CH;
  const int b     = bh / CH;

  const size_t rowbase = ((size_t)b * CD + (size_t)(hh * HD + slice * 8)) * (size_t)CN
                       + (size_t)gg;
  const float* qb = q + rowbase;
  const float* kb = k + rowbase;
  const float* vb = v + rowbase;

  // ---- partial scores over this slice's 8 dd (fully unrolled)
  float s00 = 0.f, s01 = 0.f, s02 = 0.f;
  float s10 = 0.f, s11 = 0.f, s12 = 0.f;
  float s20 = 0.f, s21 = 0.f, s22 = 0.f;
  #pragma unroll
  for (int d = 0; d < 8; ++d) {
    const float* qp = qb + (size_t)d * CN;
    const float* kp = kb + (size_t)d * CN;
    const float q0 = qp[0], q1 = qp[CG], q2 = qp[2 * CG];
    const float k0 = kp[0], k1 = kp[CG], k2 = kp[2 * CG];
    s00 = fmaf(q0, k0, s00); s01 = fmaf(q0, k1, s01); s02 = fmaf(q0, k2, s02);
    s10 = fmaf(q1, k0, s10); s11 = fmaf(q1, k1, s11); s12 = fmaf(q1, k2, s12);
    s20 = fmaf(q2, k0, s20); s21 = fmaf(q2, k1, s21); s22 = fmaf(q2, k2, s22);
  }

  // ---- issue v loads NOW; their latency hides under shuffles + softmax
  float v0v[8], v1v[8], v2v[8];
  #pragma unroll
  for (int d = 0; d < 8; ++d) {
    const float* vp = vb + (size_t)d * CN;
    v0v[d] = vp[0]; v1v[d] = vp[CG]; v2v[d] = vp[2 * CG];
  }

  // ---- combine partial scores across the 4 slices (lanes ^16, ^32)
  s00 += __shfl_xor(s00, 16); s01 += __shfl_xor(s01, 16); s02 += __shfl_xor(s02, 16);
  s10 += __shfl_xor(s10, 16); s11 += __shfl_xor(s11, 16); s12 += __shfl_xor(s12, 16);
  s20 += __shfl_xor(s20, 16); s21 += __shfl_xor(s21, 16); s22 += __shfl_xor(s22, 16);
  s00 += __shfl_xor(s00, 32); s01 += __shfl_xor(s01, 32); s02 += __shfl_xor(s02, 32);
  s10 += __shfl_xor(s10, 32); s11 += __shfl_xor(s11, 32); s12 += __shfl_xor(s12, 32);
  s20 += __shfl_xor(s20, 32); s21 += __shfl_xor(s21, 32); s22 += __shfl_xor(s22, 32);

  const float scale = 0.17677669529663687f;  // 32^-0.5
  s00 *= scale; s01 *= scale; s02 *= scale;
  s10 *= scale; s11 *= scale; s12 *= scale;
  s20 *= scale; s21 *= scale; s22 *= scale;

  // ---- softmax over kj, per row kq (redundant in all 4 slices)
  const float m0 = fmaxf(fmaxf(s00, s01), s02);
  const float m1 = fmaxf(fmaxf(s10, s11), s12);
  const float m2 = fmaxf(fmaxf(s20, s21), s22);
  const float e00 = __expf(s00 - m0), e01 = __expf(s01 - m0), e02 = __expf(s02 - m0);
  const float e10 = __expf(s10 - m1), e11 = __expf(s11 - m1), e12 = __expf(s12 - m1);
  const float e20 = __expf(s20 - m2), e21 = __expf(s21 - m2), e22 = __expf(s22 - m2);
  const float r0 = 1.f / (e00 + e01 + e02);
  const float r1 = 1.f / (e10 + e11 + e12);
  const float r2 = 1.f / (e20 + e21 + e22);
  const float p00 = e00 * r0, p01 = e01 * r0, p02 = e02 * r0;
  const float p10 = e10 * r1, p11 = e11 * r1, p12 = e12 * r1;
  const float p20 = e20 * r2, p21 = e21 * r2, p22 = e22 * r2;

  // ---- PV from registers + store, row by row (o reused per row)
  float* ob = out + ((size_t)b * CG + (size_t)gg) * (size_t)(CH * KS * HD)
                  + (size_t)hh * (KS * HD) + (size_t)slice * 8;

  float o[8];
  #pragma unroll
  for (int d = 0; d < 8; ++d)
    o[d] = fmaf(p00, v0v[d], fmaf(p01, v1v[d], p02 * v2v[d]));
  *reinterpret_cast<float4*>(ob + 0 * HD + 0) = make_float4(o[0], o[1], o[2], o[3]);
  *reinterpret_cast<float4*>(ob + 0 * HD + 4) = make_float4(o[4], o[5], o[6], o[7]);

  #pragma unroll
  for (int d = 0; d < 8; ++d)
    o[d] = fmaf(p10, v0v[d], fmaf(p11, v1v[d], p12 * v2v[d]));
  *reinterpret_cast<float4*>(ob + 1 * HD + 0) = make_float4(o[0], o[1], o[2], o[3]);
  *reinterpret_cast<float4*>(ob + 1 * HD + 4) = make_float4(o[4], o[5], o[6], o[7]);

  #pragma unroll
  for (int d = 0; d < 8; ++d)
    o[d] = fmaf(p20, v0v[d], fmaf(p21, v1v[d], p22 * v2v[d]));
  *reinterpret_cast<float4*>(ob + 2 * HD + 0) = make_float4(o[0], o[1], o[2], o[3]);
  *reinterpret_cast<float4*>(ob + 2 * HD + 4) = make_float4(o[4], o[5], o[6], o[7]);
}

extern "C" void kernel_launch(void* const* d_in, const int* in_sizes, int n_in,
                              void* d_out, int out_size, void* d_ws, size_t ws_size,
                              hipStream_t stream) {
  const float* q = (const float*)d_in[0];
  const float* k = (const float*)d_in[1];
  const float* v = (const float*)d_in[2];
  float* out = (float*)d_out;

  const int total = CB * CH * CG * 4;        // 1572864 threads, 4 per window
  const int blocks = total / 256;            // 6144 blocks = 24576 waves
  dilate_attn_kernel<<<blocks, 256, 0, stream>>>(q, k, v, out);
}